// Round 2
// baseline (303.472 us; speedup 1.0000x reference)
//
#include <hip/hip_runtime.h>

#define BATCH 32
#define EMB_DIM 256
#define HW 4096
#define N_EMB 1024
#define N_ROWS (BATCH * HW)            // 131072
#define TOT_ELEMS (N_ROWS * EMB_DIM)   // 33554432

typedef __attribute__((ext_vector_type(8))) short bf16x8;
typedef __attribute__((ext_vector_type(4))) float f32x4;

// ws layout (bytes)
#define WS_EMB_OFF 0              // 512 KB swizzled bf16 emb
#define WS_E2_OFF  524288         // 1024 f32 (sum of squares per emb)
#define WS_PSC_OFF 528384         // 256 f32 vq-kernel partials

#define MAIN_BLOCKS 256           // 512 rows per block (8 waves x 32 rows x 2 sub-batches)

__device__ __forceinline__ unsigned short f2bf(float f) {
    unsigned int u = __builtin_bit_cast(unsigned int, f);
    u += 0x7FFFu + ((u >> 16) & 1u);   // round-to-nearest-even
    return (unsigned short)(u >> 16);
}

typedef const __attribute__((address_space(1))) unsigned int* gas_u32p;
typedef __attribute__((address_space(3))) unsigned int* las_u32p;
__device__ __forceinline__ void gll16(const void* g, void* l) {
    __builtin_amdgcn_global_load_lds((gas_u32p)g, (las_u32p)l, 16, 0, 0);
}

// ---------------------------------------------------------------------------
// Kernel 0: emb fp32 -> bf16, pre-swizzled chunk layout + e2 = ||e||^2.
// chunk = e>>6 (64 e per 32KB chunk), row el = e&63 (512B rows),
// byte cb within row stored at cb ^ ((el&31)<<4).   (verified round 1: 0 bank conflicts)
// ---------------------------------------------------------------------------
__global__ __launch_bounds__(64) void prep_emb(const float* __restrict__ emb,
                                               unsigned long long* __restrict__ embsw,
                                               float* __restrict__ e2) {
    const int e = blockIdx.x, ln = threadIdx.x;
    const float4 v = reinterpret_cast<const float4*>(emb)[e * 64 + ln];
    float s = v.x * v.x + v.y * v.y + v.z * v.z + v.w * v.w;

    unsigned long long pk = (unsigned long long)f2bf(v.x)
                          | ((unsigned long long)f2bf(v.y) << 16)
                          | ((unsigned long long)f2bf(v.z) << 32)
                          | ((unsigned long long)f2bf(v.w) << 48);
    const int el = e & 63, ch = e >> 6;
    const int cb = ln * 8;
    const int off = (ch << 15) + (el << 9) + (cb ^ ((el & 31) << 4));
    *reinterpret_cast<unsigned long long*>(reinterpret_cast<char*>(embsw) + off) = pk;

#pragma unroll
    for (int o = 32; o; o >>= 1) s += __shfl_down(s, o);
    if (ln == 0) e2[e] = s;
}

// ---------------------------------------------------------------------------
// Kernel 1: fused copy + sum(x^2) + GEMM + min-reduction.
// 8 waves x 512 rows/block; 2 sub-batches of 32 rows/wave pipelined:
// sub-batch 1's HBM IO (load x, store out, cvt bf16) is burst-issued inside
// sub-batch 0's e-chunk loop. emb staged to LDS via global_load_lds (dbuf).
// MFMA 16x16x32 bf16, A=emb (LDS, swizzled), B=x rows (regs).
// ---------------------------------------------------------------------------
__global__ __attribute__((amdgpu_flat_work_group_size(512, 512), amdgpu_waves_per_eu(2, 2)))
void vq_main(const float* __restrict__ x,
             float* __restrict__ out,
             const uint4* __restrict__ embsw,
             const float* __restrict__ e2,
             float* __restrict__ psc) {
    __shared__ uint4 smem4[4096];          // 2 x 32KB emb chunk buffers
    const int tid = threadIdx.x;
    const int wv = tid >> 6, ln = tid & 63;
    const int u = ln & 15, g = ln >> 4;    // m-lane, k-group

    const int row_base = blockIdx.x << 9;                 // 512 rows/block
    const int b = row_base >> 12, n_base = row_base & 4095;
    const int base_off = b * (EMB_DIM * HW) + n_base + wv * 32 + u;
    const float* xb = x + base_off;
    float*       ob = out + base_off;
    const float* xb1 = xb + 256;           // sub-batch 1 (n += 256)
    float*       ob1 = ob + 256;

#define STAGE_EMB(CC, BUF) do {                                              \
        const uint4* gsrc_ = embsw + (CC) * 2048 + wv * 64 + ln;             \
        char* lb_ = ((char*)smem4) + (BUF) * 32768 + wv * 1024;              \
        _Pragma("unroll")                                                    \
        for (int i_ = 0; i_ < 4; ++i_)                                       \
            gll16(gsrc_ + i_ * 512, lb_ + i_ * 8192);                        \
    } while (0)

    // issue emb chunk 0 staging first — overlaps the whole x prologue
    STAGE_EMB(0, 0);

    float x2s = 0.f;
    bf16x8 bx[2][2][8];

    // ---- sub-batch 0 IO: load x, store out, convert to fragments ----
#pragma unroll
    for (int s_ = 0; s_ < 2; ++s_)
#pragma unroll
        for (int kf = 0; kf < 8; ++kf) {
            const int ko = (kf * 32 + g * 8) * HW + s_ * 16;
            const float* p = xb + ko;
            float* q = ob + ko;
            bf16x8 v;
#pragma unroll
            for (int j = 0; j < 8; ++j) {
                float f = p[j * HW];
                q[j * HW] = f;
                x2s += f * f;
                v[j] = (short)f2bf(f);
            }
            bx[0][s_][kf] = v;
        }

#define IOG(S_, KF) do {                                                     \
        const int ko_ = ((KF) * 32 + g * 8) * HW + (S_) * 16;                \
        const float* p_ = xb1 + ko_;                                         \
        float* q_ = ob1 + ko_;                                               \
        bf16x8 v_;                                                           \
        _Pragma("unroll")                                                    \
        for (int j_ = 0; j_ < 8; ++j_) {                                     \
            float f_ = p_[j_ * HW];                                          \
            q_[j_ * HW] = f_;                                                \
            x2s += f_ * f_;                                                  \
            v_[j_] = (short)f2bf(f_);                                        \
        }                                                                    \
        bx[1][S_][KF] = v_;                                                  \
    } while (0)

    __syncthreads();   // chunk 0 staged (barrier drains vmcnt), prologue done

    const char* smemb = reinterpret_cast<const char*>(smem4);
    float contrib = 0.f;

#pragma unroll
    for (int sb = 0; sb < 2; ++sb) {
        float b0 = 3.0e38f, b1 = 3.0e38f;
        for (int c = 0; c < 16; ++c) {
            // stage next chunk (cyclic across sub-batches; none after last use)
            if (sb == 0 || c < 15) STAGE_EMB((c + 1) & 15, (c + 1) & 1);

            // sub-batch 1 IO bursts, spread across sub-batch 0's e-loop
            if (sb == 0) {
                if (c == 2)  { IOG(0, 0); IOG(0, 1); IOG(0, 2); IOG(0, 3); }
                if (c == 6)  { IOG(0, 4); IOG(0, 5); IOG(0, 6); IOG(0, 7); }
                if (c == 10) { IOG(1, 0); IOG(1, 1); IOG(1, 2); IOG(1, 3); }
                if (c == 14) { IOG(1, 4); IOG(1, 5); IOG(1, 6); IOG(1, 7); }
            }

            const char* bufb = smemb + (c & 1) * 32768;
#pragma unroll
            for (int t = 0; t < 4; ++t) {
                const int el = t * 16 + u;
                const f32x4 ev = *reinterpret_cast<const f32x4*>(e2 + c * 64 + t * 16 + g * 4);
                f32x4 a0 = {0.f, 0.f, 0.f, 0.f}, a1 = a0;
#pragma unroll
                for (int kf = 0; kf < 8; ++kf) {
                    const int off = el * 512 + ((kf * 64 + g * 16) ^ ((el & 31) << 4));
                    const bf16x8 a = *reinterpret_cast<const bf16x8*>(bufb + off);
                    a0 = __builtin_amdgcn_mfma_f32_16x16x32_bf16(a, bx[sb][0][kf], a0, 0, 0, 0);
                    a1 = __builtin_amdgcn_mfma_f32_16x16x32_bf16(a, bx[sb][1][kf], a1, 0, 0, 0);
                }
#pragma unroll
                for (int r = 0; r < 4; ++r) {
                    b0 = fminf(b0, fmaf(-2.f, a0[r], ev[r]));
                    b1 = fminf(b1, fmaf(-2.f, a1[r], ev[r]));
                }
            }
            __syncthreads();   // drains gll vmcnt + all waves done with bufb
        }
        // combine the 4 g-lane copies (each holds a disjoint e-subset's min)
        b0 = fminf(b0, __shfl_xor(b0, 16));
        b0 = fminf(b0, __shfl_xor(b0, 32));
        b1 = fminf(b1, __shfl_xor(b1, 16));
        b1 = fminf(b1, __shfl_xor(b1, 32));
        if (g == 0) contrib += b0 + b1;
    }

    contrib += x2s;
#pragma unroll
    for (int o = 32; o; o >>= 1) contrib += __shfl_down(contrib, o);

    float* wsf = reinterpret_cast<float*>(smem4);   // reuse LDS (emb done)
    if (ln == 0) wsf[wv] = contrib;
    __syncthreads();
    if (tid == 0) {
        float s = 0.f;
#pragma unroll
        for (int i = 0; i < 8; ++i) s += wsf[i];
        psc[blockIdx.x] = s;
    }
#undef STAGE_EMB
#undef IOG
}

// ---------------------------------------------------------------------------
// Kernel 2: deterministic tree-reduce of partials -> loss scalar.
// ---------------------------------------------------------------------------
__global__ __launch_bounds__(256) void finalize(const float* __restrict__ psc,
                                                float* __restrict__ out_loss) {
    __shared__ float red[256];
    const int t = threadIdx.x;
    red[t] = psc[t];
    __syncthreads();
    for (int h = 128; h; h >>= 1) {
        if (t < h) red[t] += red[t + h];
        __syncthreads();
    }
    if (t == 0) *out_loss = 1.25f * red[0] / (float)TOT_ELEMS;
}

extern "C" void kernel_launch(void* const* d_in, const int* in_sizes, int n_in,
                              void* d_out, int out_size, void* d_ws, size_t ws_size,
                              hipStream_t stream) {
    const float* x = (const float*)d_in[0];
    const float* emb = (const float*)d_in[1];
    float* out = (float*)d_out;
    char* ws = (char*)d_ws;

    unsigned long long* embsw = (unsigned long long*)(ws + WS_EMB_OFF);
    float* e2  = (float*)(ws + WS_E2_OFF);
    float* psc = (float*)(ws + WS_PSC_OFF);

    prep_emb<<<N_EMB, 64, 0, stream>>>(emb, embsw, e2);
    vq_main<<<MAIN_BLOCKS, 512, 0, stream>>>(x, out, (const uint4*)(ws + WS_EMB_OFF), e2, psc);
    finalize<<<1, 256, 0, stream>>>(psc, out + TOT_ELEMS);
}

// Round 3
// 236.026 us; speedup vs baseline: 1.2858x; 1.2858x over previous
//
#include <hip/hip_runtime.h>

#define EMB_DIM 256
#define HW 4096
#define N_EMB 1024
#define TOT_ELEMS (32 * HW * EMB_DIM)   // 33554432

typedef __attribute__((ext_vector_type(8))) short bf16x8;
typedef __attribute__((ext_vector_type(4))) float f32x4;

// ws layout (bytes)
#define WS_EMB_OFF 0              // 512 KB fragment-linear bf16 emb
#define WS_E2_OFF  524288         // 1024 f32 ||e||^2
#define WS_PSC_OFF 528384         // 1024 f32 block partials

#define MAIN_BLOCKS 1024          // 128 rows/block, 4 waves x 32 rows

__device__ __forceinline__ unsigned short f2bf(float f) {
    unsigned int u = __builtin_bit_cast(unsigned int, f);
    u += 0x7FFFu + ((u >> 16) & 1u);   // round-to-nearest-even
    return (unsigned short)(u >> 16);
}

// ---------------------------------------------------------------------------
// Kernel 0: emb fp32 -> bf16 in MFMA-FRAGMENT-LINEAR order + e2 = ||e||^2.
// For e-tile t=e>>4, frag kf, MFMA lane l = (e&15) + 16*g holds
// emb[e][kf*32 + g*8 + j], j=0..7, stored at byte ((t*8+kf)*64 + l)*16.
// Thread ln covers k = 4*ln..4*ln+3: kf=ln>>3, g=(ln>>1)&3, half=ln&1.
// ---------------------------------------------------------------------------
__global__ __launch_bounds__(64) void prep_emb(const float* __restrict__ emb,
                                               unsigned long long* __restrict__ embf,
                                               float* __restrict__ e2) {
    const int e = blockIdx.x, ln = threadIdx.x;
    const float4 v = reinterpret_cast<const float4*>(emb)[e * 64 + ln];
    float s = v.x * v.x + v.y * v.y + v.z * v.z + v.w * v.w;

    unsigned long long pk = (unsigned long long)f2bf(v.x)
                          | ((unsigned long long)f2bf(v.y) << 16)
                          | ((unsigned long long)f2bf(v.z) << 32)
                          | ((unsigned long long)f2bf(v.w) << 48);
    const int t = e >> 4, er = e & 15;
    const int kf = ln >> 3, g = (ln >> 1) & 3, half = ln & 1;
    const int off = (((t * 8 + kf) * 64) + (er + 16 * g)) * 16 + half * 8;
    *reinterpret_cast<unsigned long long*>(reinterpret_cast<char*>(embf) + off) = pk;

#pragma unroll
    for (int o = 32; o; o >>= 1) s += __shfl_down(s, o);
    if (ln == 0) e2[e] = s;
}

// ---------------------------------------------------------------------------
// Kernel 1: fused copy + sum(x^2) + GEMM + min-reduction. NO LDS, NO barriers
// in the hot loop: x rows live in 64 VGPRs/wave, emb A-fragments stream from
// global (L2-resident, fragment-linear => coalesced dwordx4).
// MFMA 16x16x32 bf16: A=emb tile(16e x 32k), B=x(32k x 16m),
// D[e][m]: m=lane&15, e=4*(lane>>4)+reg.
// ---------------------------------------------------------------------------
__global__ __launch_bounds__(256, 4)
void vq_main(const float* __restrict__ x,
             float* __restrict__ out,
             const bf16x8* __restrict__ embf,
             const float* __restrict__ e2,
             float* __restrict__ psc) {
    const int tid = threadIdx.x;
    const int wv = tid >> 6, ln = tid & 63;
    const int u = ln & 15, g = ln >> 4;        // m-lane, k-octet group

    const int row_base = blockIdx.x << 7;      // 128 rows/block
    const int b = row_base >> 12, n_base = row_base & 4095;
    const int base0 = b * (EMB_DIM * HW) + n_base + wv * 32 + u;
    const float* p0 = x + base0;               // row-set 0: m = u
    float* q0 = out + base0;                   // row-set 1: +16

    // ---- load x once: copy to out, accumulate x^2, build B-fragments ----
    float x2s = 0.f;
    bf16x8 bx0[8], bx1[8];
#pragma unroll
    for (int kf = 0; kf < 8; ++kf) {
        bf16x8 v0, v1;
#pragma unroll
        for (int j = 0; j < 8; ++j) {
            const int o = (kf * 32 + g * 8 + j) * HW;
            const float f0 = p0[o];
            const float f1 = p0[o + 16];
            q0[o] = f0;                        // both halves of each 128B line
            q0[o + 16] = f1;                   // written back-to-back
            x2s += f0 * f0 + f1 * f1;
            v0[j] = (short)f2bf(f0);
            v1[j] = (short)f2bf(f1);
        }
        bx0[kf] = v0;
        bx1[kf] = v1;
    }

    // ---- stream all 64 e-tiles; per tile: 8 coalesced A-frag loads, 16 MFMA
    float b0 = 3.0e38f, b1 = 3.0e38f;
    const bf16x8* ef = embf + ln;
    for (int t = 0; t < 64; ++t) {
        f32x4 a0 = {0.f, 0.f, 0.f, 0.f}, a1 = a0;
#pragma unroll
        for (int kf = 0; kf < 8; ++kf) {
            const bf16x8 a = ef[(t * 8 + kf) * 64];
            a0 = __builtin_amdgcn_mfma_f32_16x16x32_bf16(a, bx0[kf], a0, 0, 0, 0);
            a1 = __builtin_amdgcn_mfma_f32_16x16x32_bf16(a, bx1[kf], a1, 0, 0, 0);
        }
        const f32x4 ev = *reinterpret_cast<const f32x4*>(e2 + t * 16 + g * 4);
#pragma unroll
        for (int r = 0; r < 4; ++r) {
            b0 = fminf(b0, fmaf(-2.f, a0[r], ev[r]));
            b1 = fminf(b1, fmaf(-2.f, a1[r], ev[r]));
        }
    }

    // combine the 4 g-lane copies (each saw a disjoint quarter of the e's)
    b0 = fminf(b0, __shfl_xor(b0, 16));
    b0 = fminf(b0, __shfl_xor(b0, 32));
    b1 = fminf(b1, __shfl_xor(b1, 16));
    b1 = fminf(b1, __shfl_xor(b1, 32));

    float contrib = x2s + ((g == 0) ? (b0 + b1) : 0.f);
#pragma unroll
    for (int o = 32; o; o >>= 1) contrib += __shfl_down(contrib, o);

    __shared__ float wsum[4];
    if (ln == 0) wsum[wv] = contrib;
    __syncthreads();
    if (tid == 0) psc[blockIdx.x] = (wsum[0] + wsum[1]) + (wsum[2] + wsum[3]);
}

// ---------------------------------------------------------------------------
// Kernel 2: deterministic tree-reduce of partials -> loss scalar.
// ---------------------------------------------------------------------------
__global__ __launch_bounds__(256) void finalize(const float* __restrict__ psc,
                                                float* __restrict__ out_loss) {
    __shared__ float red[256];
    const int t = threadIdx.x;
    float s = 0.f;
#pragma unroll
    for (int i = 0; i < MAIN_BLOCKS / 256; ++i) s += psc[t + i * 256];
    red[t] = s;
    __syncthreads();
    for (int h = 128; h; h >>= 1) {
        if (t < h) red[t] += red[t + h];
        __syncthreads();
    }
    if (t == 0) *out_loss = 1.25f * red[0] / (float)TOT_ELEMS;
}

extern "C" void kernel_launch(void* const* d_in, const int* in_sizes, int n_in,
                              void* d_out, int out_size, void* d_ws, size_t ws_size,
                              hipStream_t stream) {
    const float* x = (const float*)d_in[0];
    const float* emb = (const float*)d_in[1];
    float* out = (float*)d_out;
    char* ws = (char*)d_ws;

    unsigned long long* embf = (unsigned long long*)(ws + WS_EMB_OFF);
    float* e2  = (float*)(ws + WS_E2_OFF);
    float* psc = (float*)(ws + WS_PSC_OFF);

    prep_emb<<<N_EMB, 64, 0, stream>>>(emb, embf, e2);
    vq_main<<<MAIN_BLOCKS, 256, 0, stream>>>(x, out, (const bf16x8*)(ws + WS_EMB_OFF), e2, psc);
    finalize<<<1, 256, 0, stream>>>(psc, out + TOT_ELEMS);
}

// Round 4
// 136.747 us; speedup vs baseline: 2.2192x; 1.7260x over previous
//
#include <hip/hip_runtime.h>

#define EMB_DIM 256
#define HW 4096
#define N_EMB 1024
#define TOT_ELEMS (32 * HW * EMB_DIM)   // 33554432

typedef __attribute__((ext_vector_type(8))) short bf16x8;
typedef __attribute__((ext_vector_type(4))) float f32x4;

// ws layout (bytes)
#define WS_EMB_OFF 0              // 512 KB swizzled bf16 emb (chunk layout)
#define WS_E2_OFF  524288         // 1024 f32 ||e||^2
#define WS_PSC_OFF 528384         // 1024 f32 block partials

#define MAIN_BLOCKS 1024          // 128 rows/block, 4 waves x 32 rows

__device__ __forceinline__ unsigned short f2bf(float f) {
    unsigned int u = __builtin_bit_cast(unsigned int, f);
    u += 0x7FFFu + ((u >> 16) & 1u);   // round-to-nearest-even
    return (unsigned short)(u >> 16);
}

typedef const __attribute__((address_space(1))) unsigned int* gas_u32p;
typedef __attribute__((address_space(3))) unsigned int* las_u32p;
__device__ __forceinline__ void gll16(const void* g, void* l) {
    __builtin_amdgcn_global_load_lds((gas_u32p)g, (las_u32p)l, 16, 0, 0);
}

// ---------------------------------------------------------------------------
// Kernel 0: emb fp32 -> bf16, pre-swizzled chunk layout + e2 = ||e||^2.
// chunk = e>>6 (64 e per 32KB chunk), row el = e&63 (512B rows),
// byte cb within row stored at cb ^ ((el&31)<<4).
// (verified rounds 1-2: correct + 0 LDS bank conflicts on the paired reader)
// ---------------------------------------------------------------------------
__global__ __launch_bounds__(64) void prep_emb(const float* __restrict__ emb,
                                               unsigned long long* __restrict__ embsw,
                                               float* __restrict__ e2) {
    const int e = blockIdx.x, ln = threadIdx.x;
    const float4 v = reinterpret_cast<const float4*>(emb)[e * 64 + ln];
    float s = v.x * v.x + v.y * v.y + v.z * v.z + v.w * v.w;

    unsigned long long pk = (unsigned long long)f2bf(v.x)
                          | ((unsigned long long)f2bf(v.y) << 16)
                          | ((unsigned long long)f2bf(v.z) << 32)
                          | ((unsigned long long)f2bf(v.w) << 48);
    const int el = e & 63, ch = e >> 6;
    const int cb = ln * 8;
    const int off = (ch << 15) + (el << 9) + (cb ^ ((el & 31) << 4));
    *reinterpret_cast<unsigned long long*>(reinterpret_cast<char*>(embsw) + off) = pk;

#pragma unroll
    for (int o = 32; o; o >>= 1) s += __shfl_down(s, o);
    if (ln == 0) e2[e] = s;
}

// ---------------------------------------------------------------------------
// Kernel 1: fused copy + sum(x^2) + GEMM + min-reduction.
// 4 waves x 32 rows/wave. x-fragments are FORCED into AGPRs via empty
// asm "+a" laundering (the 3-round-running spill cause). emb staged to LDS
// by global_load_lds from the pre-swizzled source, double-buffered,
// 1 barrier per 32KB chunk. MFMA 16x16x32 bf16, A=emb (LDS), B=x (AGPR).
// D[e][m]: m=lane&15, e=4*(lane>>4)+reg.
// ---------------------------------------------------------------------------
__global__ __launch_bounds__(256)
void vq_main(const float* __restrict__ x,
             float* __restrict__ out,
             const uint4* __restrict__ embsw,
             const float* __restrict__ e2,
             float* __restrict__ psc) {
    __shared__ uint4 smem4[4096];          // 2 x 32KB emb chunk buffers
    const int tid = threadIdx.x;
    const int wv = tid >> 6, ln = tid & 63;
    const int u = ln & 15, g = ln >> 4;    // m-lane, k-octet group

    const int row_base = blockIdx.x << 7;  // 128 rows/block
    const int b = row_base >> 12, n_base = row_base & 4095;
    const int base0 = b * (EMB_DIM * HW) + n_base + wv * 32 + u;
    const float* p0 = x + base0;           // row-set 0: m = u
    float* q0 = out + base0;               // row-set 1: +16

    // ---- stage emb chunk 0 (L2-resident; overlaps the whole x prologue) ----
    {
        const uint4* gs = embsw + wv * 64 + ln;
        char* lb = (char*)smem4 + wv * 1024;
#pragma unroll
        for (int i = 0; i < 8; ++i) gll16(gs + i * 256, lb + i * 4096);
    }

    // ---- load x once: copy to out, accumulate x^2, build B-fragments ----
    float x2s = 0.f;
    bf16x8 bx0[8], bx1[8];
#pragma unroll
    for (int kf = 0; kf < 8; ++kf) {
        bf16x8 v0, v1;
#pragma unroll
        for (int j = 0; j < 8; ++j) {
            const int o = (kf * 32 + g * 8 + j) * HW;
            const float f0 = p0[o];
            const float f1 = p0[o + 16];
            q0[o] = f0;
            q0[o + 16] = f1;
            x2s += f0 * f0 + f1 * f1;
            v0[j] = (short)f2bf(f0);
            v1[j] = (short)f2bf(f1);
        }
        bx0[kf] = v0;
        bx1[kf] = v1;
        // pin the persistent fragments into AGPRs — arch-VGPR pressure drops
        // below the spill threshold by construction
        asm volatile("" : "+a"(bx0[kf]), "+a"(bx1[kf]));
    }

    __syncthreads();   // chunk 0 staged (barrier drains vmcnt)

    const char* smemb = reinterpret_cast<const char*>(smem4);
    float b0 = 3.0e38f, b1 = 3.0e38f;

    for (int c = 0; c < 16; ++c) {
        if (c < 15) {  // stage next chunk into the other buffer
            const uint4* gs = embsw + (c + 1) * 2048 + wv * 64 + ln;
            char* lb = (char*)smem4 + ((c + 1) & 1) * 32768 + wv * 1024;
#pragma unroll
            for (int i = 0; i < 8; ++i) gll16(gs + i * 256, lb + i * 4096);
        }
        const char* bufb = smemb + (c & 1) * 32768;
#pragma unroll
        for (int t = 0; t < 4; ++t) {
            const int el = t * 16 + u;
            f32x4 a0 = {0.f, 0.f, 0.f, 0.f}, a1 = a0;
#pragma unroll
            for (int kf = 0; kf < 8; ++kf) {
                const int off = el * 512 + ((kf * 64 + g * 16) ^ ((el & 31) << 4));
                const bf16x8 a = *reinterpret_cast<const bf16x8*>(bufb + off);
                a0 = __builtin_amdgcn_mfma_f32_16x16x32_bf16(a, bx0[kf], a0, 0, 0, 0);
                a1 = __builtin_amdgcn_mfma_f32_16x16x32_bf16(a, bx1[kf], a1, 0, 0, 0);
            }
            const f32x4 ev = *reinterpret_cast<const f32x4*>(e2 + c * 64 + t * 16 + g * 4);
#pragma unroll
            for (int r = 0; r < 4; ++r) {
                b0 = fminf(b0, fmaf(-2.f, a0[r], ev[r]));
                b1 = fminf(b1, fmaf(-2.f, a1[r], ev[r]));
            }
        }
        __syncthreads();   // all waves done with bufb; gll(c+1) drained
    }

    // combine the 4 g-lane copies (each saw a disjoint quarter of the e's)
    b0 = fminf(b0, __shfl_xor(b0, 16));
    b0 = fminf(b0, __shfl_xor(b0, 32));
    b1 = fminf(b1, __shfl_xor(b1, 16));
    b1 = fminf(b1, __shfl_xor(b1, 32));

    float contrib = x2s + ((g == 0) ? (b0 + b1) : 0.f);
#pragma unroll
    for (int o = 32; o; o >>= 1) contrib += __shfl_down(contrib, o);

    float* wsf = reinterpret_cast<float*>(smem4);   // safe: post-loop barrier
    if (ln == 0) wsf[wv] = contrib;
    __syncthreads();
    if (tid == 0) psc[blockIdx.x] = (wsf[0] + wsf[1]) + (wsf[2] + wsf[3]);
}

// ---------------------------------------------------------------------------
// Kernel 2: deterministic tree-reduce of partials -> loss scalar.
// ---------------------------------------------------------------------------
__global__ __launch_bounds__(256) void finalize(const float* __restrict__ psc,
                                                float* __restrict__ out_loss) {
    __shared__ float red[256];
    const int t = threadIdx.x;
    float s = 0.f;
#pragma unroll
    for (int i = 0; i < MAIN_BLOCKS / 256; ++i) s += psc[t + i * 256];
    red[t] = s;
    __syncthreads();
    for (int h = 128; h; h >>= 1) {
        if (t < h) red[t] += red[t + h];
        __syncthreads();
    }
    if (t == 0) *out_loss = 1.25f * red[0] / (float)TOT_ELEMS;
}

extern "C" void kernel_launch(void* const* d_in, const int* in_sizes, int n_in,
                              void* d_out, int out_size, void* d_ws, size_t ws_size,
                              hipStream_t stream) {
    const float* x = (const float*)d_in[0];
    const float* emb = (const float*)d_in[1];
    float* out = (float*)d_out;
    char* ws = (char*)d_ws;

    unsigned long long* embsw = (unsigned long long*)(ws + WS_EMB_OFF);
    float* e2  = (float*)(ws + WS_E2_OFF);
    float* psc = (float*)(ws + WS_PSC_OFF);

    prep_emb<<<N_EMB, 64, 0, stream>>>(emb, embsw, e2);
    vq_main<<<MAIN_BLOCKS, 256, 0, stream>>>(x, out, (const uint4*)(ws + WS_EMB_OFF), e2, psc);
    finalize<<<1, 256, 0, stream>>>(psc, out + TOT_ELEMS);
}